// Round 7
// baseline (87169.513 us; speedup 1.0000x reference)
//
#include <hip/hip_runtime.h>
#include <cstdint>
#include <cstddef>

#define NWG 64
#define NTHR 1024
#define UPW 16  // hidden units per WG
#define TSTEPS 16384
#define HDIM 1024
#define EDIM 13
#define HLDIM 512

typedef unsigned long long ull;

// ---------------------------------------------------------------------------
// Init kernel: re-arm the tagged h-record ring and u-record every call (d_ws
// is poisoned once with 0xAA and never re-poisoned between graph replays; a
// finished replay also leaves end-state tags behind, so every tag word must
// be rewritten each launch).
// hrec[parity][i] = { low32: f32 h value, high32: u32 step tag }, 4 parities.
// ---------------------------------------------------------------------------
__global__ void k_init(const float* __restrict__ h0, ull* __restrict__ hrec,
                       ull* __restrict__ urec) {
  int i = threadIdx.x;  // 1024 threads
  hrec[i] = (ull)__float_as_uint(h0[i]);  // {h0, tag=0}
  hrec[HDIM + i] = 0ull;
  hrec[2 * HDIM + i] = 0ull;
  hrec[3 * HDIM + i] = 0ull;
  if (i < HLDIM) urec[i] = 0ull;
}

// ---------------------------------------------------------------------------
// Persistent LSTM kernel, hybrid W residency. 64 WGs x 1024 threads (16
// waves), 1 WG/CU (forced by ~144 KB static LDS). Wave v owns unit 16w+v.
// - units v<8: W rows in LDS (128 KB, compiler-proof residency)
// - units v>=8: W rows streamed from global each step; per-XCD working set
//   8 WGs x 128 KB = 1 MB -> L2-resident (~250 cyc), overlapped with the
//   h-fragment LDS reads. No big register arrays -> nothing to spill
//   (rounds 3-5: every VGPR-pinning attempt spilled; round 6: 128 WGs +
//   s_sleep in the poll regressed -> both reverted).
// Cross-WG sync: self-validating {value, tag} records, 4-deep parity ring,
// relaxed agent-scope 64-bit atomics (single-copy, serviced at the device
// coherent point -> immune to non-coherent per-XCD L2s). 4-deep clustered
// poll: 4 same-address loads in flight, check newest first (per-location
// coherence order makes any tag-match valid) -> detection ~1 RTT not 1.5.
// ---------------------------------------------------------------------------
__global__ __launch_bounds__(NTHR) void k_main(
    const float* __restrict__ x, const float* __restrict__ c0,
    const float* __restrict__ Wih, const float* __restrict__ Whh,
    const float* __restrict__ bih, const float* __restrict__ bhh,
    const float* __restrict__ W1, const float* __restrict__ b1,
    const float* __restrict__ W2, const float* __restrict__ b2,
    float* __restrict__ out, ull* hrec, ull* urec) {
  const int w = blockIdx.x;
  const int tid = threadIdx.x;
  const int wave = tid >> 6;  // 0..15 == local unit
  const int lane = tid & 63;

  __shared__ float4 lds_w4[32 * 256];  // units 0..7: row r=4v+g, 128 KB
  __shared__ float4 lds_h4[2 * 256];   // [parity][col4]
  __shared__ float lds_x[2][16];
  __shared__ float lds_wih[64][17];  // stride 17: conflict-free
  __shared__ float lds_bsum[64];
  __shared__ float lds_r0[8], lds_r1[8];
  float* lds_hf = (float*)lds_h4;  // [2][1024] flat

  // ---- stage W for units 0..7 into LDS (one-time, coalesced) -------------
#pragma unroll
  for (int it = 0; it < 8; ++it) {
    int idx = it * NTHR + tid;  // 0..8191 float4s
    int r = idx >> 8;           // local row 0..31 (r = 4*v + g)
    int c4 = idx & 255;
    int v_ = r >> 2, g_ = r & 3;
    int grow = g_ * HDIM + UPW * w + v_;
    lds_w4[r * 256 + c4] = ((const float4*)(Whh + (size_t)grow * HDIM))[c4];
  }
  if (tid < 64) {
    int v_ = tid >> 2, g_ = tid & 3;
    int grow = g_ * HDIM + UPW * w + v_;
#pragma unroll
    for (int e = 0; e < EDIM; ++e) lds_wih[tid][e] = Wih[grow * EDIM + e];
    lds_bsum[tid] = bih[grow] + bhh[grow];
  }
  // cell state: lane 0 of wave v owns unit 16w+v
  float cst = c0[UPW * w + wave];
  __syncthreads();

  const int myg = lane & 3;                      // gate this lane activates
  const float gsc = (myg == 2) ? 2.f : 1.f;      // tanh via 2*sigmoid(2x)-1
  const float4* wb = lds_w4 + (wave * 4) * 256;  // valid for wave<8
  // global row bases for streamed waves (wave>=8); L2-resident after step 1
  const float4* gr0 =
      (const float4*)(Whh + (size_t)(0 * HDIM + UPW * w + wave) * HDIM);
  const float4* gr1 =
      (const float4*)(Whh + (size_t)(1 * HDIM + UPW * w + wave) * HDIM);
  const float4* gr2 =
      (const float4*)(Whh + (size_t)(2 * HDIM + UPW * w + wave) * HDIM);
  const float4* gr3 =
      (const float4*)(Whh + (size_t)(3 * HDIM + UPW * w + wave) * HDIM);

  for (int t = 1; t <= TSTEPS; ++t) {
    const int lp = (t - 1) & 1;
    // ---- x_t prefetch: issue before the poll so latency hides there
    float xv = 0.f;
    if (tid < EDIM) xv = x[(size_t)(t - 1) * EDIM + tid];

    // ---- 4-deep clustered poll of this thread's ONE {h, tag} record
    const ull* rec = hrec + (size_t)((t - 1) & 3) * HDIM + tid;
    const unsigned want = (unsigned)(t - 1);
    ull v = __hip_atomic_load(rec, __ATOMIC_RELAXED, __HIP_MEMORY_SCOPE_AGENT);
    if ((unsigned)(v >> 32) != want) {
      for (;;) {
        ull pa = __hip_atomic_load(rec, __ATOMIC_RELAXED,
                                   __HIP_MEMORY_SCOPE_AGENT);
        ull pb = __hip_atomic_load(rec, __ATOMIC_RELAXED,
                                   __HIP_MEMORY_SCOPE_AGENT);
        ull pc = __hip_atomic_load(rec, __ATOMIC_RELAXED,
                                   __HIP_MEMORY_SCOPE_AGENT);
        ull pd = __hip_atomic_load(rec, __ATOMIC_RELAXED,
                                   __HIP_MEMORY_SCOPE_AGENT);
        if ((unsigned)(pd >> 32) == want) { v = pd; break; }
        if ((unsigned)(pc >> 32) == want) { v = pc; break; }
        if ((unsigned)(pb >> 32) == want) { v = pb; break; }
        if ((unsigned)(pa >> 32) == want) { v = pa; break; }
      }
    }
    lds_hf[lp * HDIM + tid] = __uint_as_float((unsigned)v);
    if (tid < EDIM) lds_x[lp][tid] = xv;
    __syncthreads();

    // ---- h fragment into registers (4 float4s, reused across 4 rows)
    const float4* hb = lds_h4 + lp * 256;
    float4 h0v = hb[lane], h1v = hb[lane + 64], h2v = hb[lane + 128],
           h3v = hb[lane + 192];

    // ---- 4 gate rows of this wave's unit: 16 W reads (LDS or L2) + 64 FMA
    float acc0, acc1, acc2, acc3;
    if (wave < 8) {
      {
        float4 a = wb[lane], b = wb[lane + 64], c = wb[lane + 128],
               d = wb[lane + 192];
        acc0 = (a.x * h0v.x + a.y * h0v.y + a.z * h0v.z + a.w * h0v.w) +
               (b.x * h1v.x + b.y * h1v.y + b.z * h1v.z + b.w * h1v.w) +
               (c.x * h2v.x + c.y * h2v.y + c.z * h2v.z + c.w * h2v.w) +
               (d.x * h3v.x + d.y * h3v.y + d.z * h3v.z + d.w * h3v.w);
      }
      {
        const float4* wr = wb + 256;
        float4 a = wr[lane], b = wr[lane + 64], c = wr[lane + 128],
               d = wr[lane + 192];
        acc1 = (a.x * h0v.x + a.y * h0v.y + a.z * h0v.z + a.w * h0v.w) +
               (b.x * h1v.x + b.y * h1v.y + b.z * h1v.z + b.w * h1v.w) +
               (c.x * h2v.x + c.y * h2v.y + c.z * h2v.z + c.w * h2v.w) +
               (d.x * h3v.x + d.y * h3v.y + d.z * h3v.z + d.w * h3v.w);
      }
      {
        const float4* wr = wb + 512;
        float4 a = wr[lane], b = wr[lane + 64], c = wr[lane + 128],
               d = wr[lane + 192];
        acc2 = (a.x * h0v.x + a.y * h0v.y + a.z * h0v.z + a.w * h0v.w) +
               (b.x * h1v.x + b.y * h1v.y + b.z * h1v.z + b.w * h1v.w) +
               (c.x * h2v.x + c.y * h2v.y + c.z * h2v.z + c.w * h2v.w) +
               (d.x * h3v.x + d.y * h3v.y + d.z * h3v.z + d.w * h3v.w);
      }
      {
        const float4* wr = wb + 768;
        float4 a = wr[lane], b = wr[lane + 64], c = wr[lane + 128],
               d = wr[lane + 192];
        acc3 = (a.x * h0v.x + a.y * h0v.y + a.z * h0v.z + a.w * h0v.w) +
               (b.x * h1v.x + b.y * h1v.y + b.z * h1v.z + b.w * h1v.w) +
               (c.x * h2v.x + c.y * h2v.y + c.z * h2v.z + c.w * h2v.w) +
               (d.x * h3v.x + d.y * h3v.y + d.z * h3v.z + d.w * h3v.w);
      }
    } else {
      // rows 0,1 first (8 loads in flight), then rows 2,3
      float4 a0 = gr0[lane], b0 = gr0[lane + 64], c0v = gr0[lane + 128],
             d0 = gr0[lane + 192];
      float4 a1 = gr1[lane], b1v = gr1[lane + 64], c1 = gr1[lane + 128],
             d1 = gr1[lane + 192];
      acc0 = (a0.x * h0v.x + a0.y * h0v.y + a0.z * h0v.z + a0.w * h0v.w) +
             (b0.x * h1v.x + b0.y * h1v.y + b0.z * h1v.z + b0.w * h1v.w) +
             (c0v.x * h2v.x + c0v.y * h2v.y + c0v.z * h2v.z + c0v.w * h2v.w) +
             (d0.x * h3v.x + d0.y * h3v.y + d0.z * h3v.z + d0.w * h3v.w);
      acc1 = (a1.x * h0v.x + a1.y * h0v.y + a1.z * h0v.z + a1.w * h0v.w) +
             (b1v.x * h1v.x + b1v.y * h1v.y + b1v.z * h1v.z + b1v.w * h1v.w) +
             (c1.x * h2v.x + c1.y * h2v.y + c1.z * h2v.z + c1.w * h2v.w) +
             (d1.x * h3v.x + d1.y * h3v.y + d1.z * h3v.z + d1.w * h3v.w);
      float4 a2 = gr2[lane], b2v = gr2[lane + 64], c2 = gr2[lane + 128],
             d2 = gr2[lane + 192];
      float4 a3 = gr3[lane], b3 = gr3[lane + 64], c3 = gr3[lane + 128],
             d3 = gr3[lane + 192];
      acc2 = (a2.x * h0v.x + a2.y * h0v.y + a2.z * h0v.z + a2.w * h0v.w) +
             (b2v.x * h1v.x + b2v.y * h1v.y + b2v.z * h1v.z + b2v.w * h1v.w) +
             (c2.x * h2v.x + c2.y * h2v.y + c2.z * h2v.z + c2.w * h2v.w) +
             (d2.x * h3v.x + d2.y * h3v.y + d2.z * h3v.z + d2.w * h3v.w);
      acc3 = (a3.x * h0v.x + a3.y * h0v.y + a3.z * h0v.z + a3.w * h0v.w) +
             (b3.x * h1v.x + b3.y * h1v.y + b3.z * h1v.z + b3.w * h1v.w) +
             (c3.x * h2v.x + c3.y * h2v.y + c3.z * h2v.z + c3.w * h2v.w) +
             (d3.x * h3v.x + d3.y * h3v.y + d3.z * h3v.z + d3.w * h3v.w);
    }

    // ---- fold x-projection + biases (lane g pre-adds into acc_g)
    if (lane < 4) {
      int lrow = wave * 4 + lane;
      float xd = lds_bsum[lrow];
#pragma unroll
      for (int e = 0; e < EDIM; ++e) xd += lds_wih[lrow][e] * lds_x[lp][e];
      if (lane == 0) acc0 += xd;
      else if (lane == 1) acc1 += xd;
      else if (lane == 2) acc2 += xd;
      else acc3 += xd;
    }

    // ---- in-wave reduce: all lanes end with all 4 gate sums
#pragma unroll
    for (int m = 1; m < 64; m <<= 1) {
      acc0 += __shfl_xor(acc0, m);
      acc1 += __shfl_xor(acc1, m);
      acc2 += __shfl_xor(acc2, m);
      acc3 += __shfl_xor(acc3, m);
    }

    // ---- activations: lane j computes gate j&3 (parallel exp chains)
    float pre = (myg == 0) ? acc0 : (myg == 1) ? acc1 : (myg == 2) ? acc2
                                                                   : acc3;
    float e = __expf(-gsc * pre);
    float y = 1.f / (1.f + e);
    float act = (myg == 2) ? 2.f * y - 1.f : y;

    float ai = __shfl(act, 0);
    float af = __shfl(act, 1);
    float ag = __shfl(act, 2);
    float ao = __shfl(act, 3);
    if (lane == 0) {
      cst = af * cst + ai * ag;
      float e2 = __expf(-2.f * cst);
      float hn = ao * (2.f / (1.f + e2) - 1.f);
      ull pk = ((ull)(unsigned)t << 32) | (ull)__float_as_uint(hn);
      __hip_atomic_store(&hrec[(size_t)(t & 3) * HDIM + UPW * w + wave], pk,
                         __ATOMIC_RELAXED, __HIP_MEMORY_SCOPE_AGENT);
    }
    // no end-of-step barrier: publish is self-validating; LDS h parity is
    // reused 2 steps later, ordered by the intervening step's barrier.
  }

  // ---- tail step 1: u = tanh(W1 @ h_T + b1), 8 rows per WG ---------------
  {
    const unsigned want = (unsigned)TSTEPS;  // parity (TSTEPS & 3) == 0
    const ull* rec = hrec + tid;
    ull v = __hip_atomic_load(rec, __ATOMIC_RELAXED, __HIP_MEMORY_SCOPE_AGENT);
    while ((unsigned)(v >> 32) != want)
      v = __hip_atomic_load(rec, __ATOMIC_RELAXED, __HIP_MEMORY_SCOPE_AGENT);
    lds_hf[tid] = __uint_as_float((unsigned)v);
  }
  __syncthreads();
  if (wave < 8) {
    int r1 = 8 * w + wave;  // one MLP row per wave, 512 rows over 64 WGs
    const float* hf = (const float*)lds_h4;
    const float* w1p = W1 + (size_t)r1 * HDIM + lane * 16;
    float a0 = 0.f, a1 = 0.f;
#pragma unroll
    for (int i = 0; i < 16; i += 2) {
      a0 += w1p[i] * hf[lane * 16 + i];
      a1 += w1p[i + 1] * hf[lane * 16 + i + 1];
    }
    float acc1 = a0 + a1;
#pragma unroll
    for (int m = 1; m < 64; m <<= 1) acc1 += __shfl_xor(acc1, m);
    if (lane == 0) {
      float e2 = __expf(-2.f * (acc1 + b1[r1]));
      float u = 2.f / (1.f + e2) - 1.f;
      ull pk = (1ull << 32) | (ull)__float_as_uint(u);
      __hip_atomic_store(&urec[r1], pk, __ATOMIC_RELAXED,
                         __HIP_MEMORY_SCOPE_AGENT);
    }
  }

  // ---- tail step 2: out = W2 @ u + b2, WG 0 only -------------------------
  if (w == 0) {
    float p0 = 0.f, p1 = 0.f;
    if (tid < HLDIM) {
      ull uv = __hip_atomic_load(&urec[tid], __ATOMIC_RELAXED,
                                 __HIP_MEMORY_SCOPE_AGENT);
      while ((unsigned)(uv >> 32) != 1u)
        uv = __hip_atomic_load(&urec[tid], __ATOMIC_RELAXED,
                               __HIP_MEMORY_SCOPE_AGENT);
      float u = __uint_as_float((unsigned)uv);
      p0 = W2[tid] * u;
      p1 = W2[HLDIM + tid] * u;
    }
#pragma unroll
    for (int m = 1; m < 64; m <<= 1) {
      p0 += __shfl_xor(p0, m);
      p1 += __shfl_xor(p1, m);
    }
    if (lane == 0 && wave < 8) {
      lds_r0[wave] = p0;
      lds_r1[wave] = p1;
    }
    __syncthreads();
    if (tid == 0) {
      float o0 = b2[0], o1 = b2[1];
#pragma unroll
      for (int k = 0; k < 8; ++k) {
        o0 += lds_r0[k];
        o1 += lds_r1[k];
      }
      out[0] = o0;
      out[1] = o1;
    }
  }
}

extern "C" void kernel_launch(void* const* d_in, const int* in_sizes, int n_in,
                              void* d_out, int out_size, void* d_ws,
                              size_t ws_size, hipStream_t stream) {
  const float* x = (const float*)d_in[0];
  const float* h0 = (const float*)d_in[1];
  const float* c0 = (const float*)d_in[2];
  const float* Wih = (const float*)d_in[3];
  const float* Whh = (const float*)d_in[4];
  const float* bih = (const float*)d_in[5];
  const float* bhh = (const float*)d_in[6];
  const float* W1 = (const float*)d_in[7];
  const float* b1 = (const float*)d_in[8];
  const float* W2 = (const float*)d_in[9];
  const float* b2 = (const float*)d_in[10];
  float* out = (float*)d_out;

  ull* hrec = (ull*)d_ws;                                    // 4*1024*8 = 32 KB
  ull* urec = (ull*)((char*)d_ws + 4 * HDIM * sizeof(ull));  // 4 KB

  k_init<<<1, 1024, 0, stream>>>(h0, hrec, urec);
  k_main<<<NWG, NTHR, 0, stream>>>(x, c0, Wih, Whh, bih, bhh, W1, b1, W2, b2,
                                   out, hrec, urec);
}

// Round 8
// 59551.160 us; speedup vs baseline: 1.4638x; 1.4638x over previous
//
#include <hip/hip_runtime.h>
#include <cstdint>
#include <cstddef>

#define NWG 64
#define NTHR 512
#define UPW 16  // hidden units per WG
#define TSTEPS 16384
#define HDIM 1024
#define EDIM 13
#define HLDIM 512

typedef unsigned long long ull;

// ---------------------------------------------------------------------------
// Init kernel: re-arm the tagged h-record ring and u-record every call (d_ws
// is poisoned once with 0xAA and never re-poisoned between graph replays; a
// finished replay also leaves end-state tags behind, so every tag word must
// be rewritten each launch).
// hrec[parity][i] = { low32: f32 h value, high32: u32 step tag }, 4 parities.
// ---------------------------------------------------------------------------
__global__ void k_init(const float* __restrict__ h0, ull* __restrict__ hrec,
                       ull* __restrict__ urec) {
  int i = threadIdx.x;  // 1024 threads
  hrec[i] = (ull)__float_as_uint(h0[i]);  // {h0, tag=0}
  hrec[HDIM + i] = 0ull;
  hrec[2 * HDIM + i] = 0ull;
  hrec[3 * HDIM + i] = 0ull;
  if (i < HLDIM) urec[i] = 0ull;
}

// ---------------------------------------------------------------------------
// Persistent LSTM kernel. R4 shell (best measured: 64 WG x 512 thr, simple
// dual-record poll, 4-parity tagged ring) + two compute fixes:
//  (a) hybrid W residency: units 0..7 in 128 KB LDS (compiler-proof; rounds
//      3-5 proved VGPR pinning always spills), units 8..15 streamed from L2
//      (8 WGs/XCD x 128 KB = 1 MB, L2-resident, coalesced 512B segments).
//  (b) contiguous [sl+32j] read pattern (R5-proven ~0 LDS bank conflicts;
//      R1-R4's broadcast pattern cost 3.4e7 conflict-cycles = ~0.86us/step).
// Wave v owns units 2v (lanes 0-31) and 2v+1 (lanes 32-63); each 32-lane
// half computes its unit's 4 gate rows, xor-reduces in-half, lanes 0-3
// compute the 4 activations in parallel, lane 0 integrates c and publishes.
// Cross-WG sync: self-validating {value, tag} 8-byte records, relaxed
// agent-scope atomics (single-copy, serviced at the device coherent point ->
// immune to non-coherent per-XCD L2s). One poll + one barrier per step.
// ---------------------------------------------------------------------------
__global__ __launch_bounds__(NTHR) void k_main(
    const float* __restrict__ x, const float* __restrict__ c0,
    const float* __restrict__ Wih, const float* __restrict__ Whh,
    const float* __restrict__ bih, const float* __restrict__ bhh,
    const float* __restrict__ W1, const float* __restrict__ b1,
    const float* __restrict__ W2, const float* __restrict__ b2,
    float* __restrict__ out, ull* hrec, ull* urec) {
  const int w = blockIdx.x;
  const int tid = threadIdx.x;
  const int wave = tid >> 6;        // 0..7
  const int lane = tid & 63;
  const int hi = lane >> 5;         // 0/1: which unit of the wave
  const int sl = lane & 31;         // sub-lane within the half
  const int lu = 2 * wave + hi;     // local unit 0..15

  __shared__ float4 lds_w4[32 * 256];  // units 0..7: row r=4*lu+g, 128 KB
  __shared__ float4 lds_h4[2 * 256];   // [parity][col4]
  __shared__ float lds_wih[64][17];    // row = 4*lu+g, stride 17
  __shared__ float lds_bsum[64];
  __shared__ float lds_r0[8], lds_r1[8];
  float* lds_hf = (float*)lds_h4;  // [2][1024] flat
  float* lds_x0 = (float*)lds_r0;  // reuse: x buffer parity 0 (16 floats)
  __shared__ float lds_xbuf[2][16];

  // ---- stage W for units 0..7 into LDS (one-time, coalesced) -------------
#pragma unroll
  for (int it = 0; it < 16; ++it) {
    int idx = it * NTHR + tid;  // 0..8191 float4s
    int r = idx >> 8;           // LDS row 0..31 (r = 4*lu + g)
    int c4 = idx & 255;
    int lu_ = r >> 2, g_ = r & 3;
    int grow = g_ * HDIM + UPW * w + lu_;
    lds_w4[r * 256 + c4] = ((const float4*)(Whh + (size_t)grow * HDIM))[c4];
  }
  if (tid < 64) {
    int lu_ = tid >> 2, g_ = tid & 3;
    int grow = g_ * HDIM + UPW * w + lu_;
#pragma unroll
    for (int e = 0; e < EDIM; ++e) lds_wih[tid][e] = Wih[grow * EDIM + e];
    lds_bsum[tid] = bih[grow] + bhh[grow];
  }
  // cell state: lane sl==0 of each half owns unit 16w+lu
  float cst = c0[UPW * w + lu];
  __syncthreads();

  const int myg = sl & 3;                    // gate computed by lanes 0..3
  const float gsc = (myg == 2) ? 2.f : 1.f;  // tanh via 2*sigmoid(2x)-1
  // W sources: LDS rows for lu<8, global rows (L2-resident) for lu>=8
  const float4* wl0 = lds_w4 + (size_t)(4 * lu + 0) * 256;  // lu<8 only
  const float4* wl1 = lds_w4 + (size_t)(4 * lu + 1) * 256;
  const float4* wl2 = lds_w4 + (size_t)(4 * lu + 2) * 256;
  const float4* wl3 = lds_w4 + (size_t)(4 * lu + 3) * 256;
  const float4* gg0 =
      (const float4*)(Whh + (size_t)(0 * HDIM + UPW * w + lu) * HDIM);
  const float4* gg1 =
      (const float4*)(Whh + (size_t)(1 * HDIM + UPW * w + lu) * HDIM);
  const float4* gg2 =
      (const float4*)(Whh + (size_t)(2 * HDIM + UPW * w + lu) * HDIM);
  const float4* gg3 =
      (const float4*)(Whh + (size_t)(3 * HDIM + UPW * w + lu) * HDIM);

  for (int t = 1; t <= TSTEPS; ++t) {
    const int lp = (t - 1) & 1;
    // ---- x_t prefetch: issue before the poll so latency hides there
    float xv = 0.f;
    if (tid < EDIM) xv = x[(size_t)(t - 1) * EDIM + tid];

    // ---- simple dual-record poll (R4-proven): both loads in flight, the
    // poll load IS the data load (one coherent round trip).
    const ull* src = hrec + (size_t)((t - 1) & 3) * HDIM;
    const unsigned want = (unsigned)(t - 1);
    ull v0 = __hip_atomic_load(&src[tid], __ATOMIC_RELAXED,
                               __HIP_MEMORY_SCOPE_AGENT);
    ull v1 = __hip_atomic_load(&src[tid + NTHR], __ATOMIC_RELAXED,
                               __HIP_MEMORY_SCOPE_AGENT);
    for (;;) {
      bool b0 = (unsigned)(v0 >> 32) == want;
      bool b1 = (unsigned)(v1 >> 32) == want;
      if (b0 && b1) break;
      if (!b0)
        v0 = __hip_atomic_load(&src[tid], __ATOMIC_RELAXED,
                               __HIP_MEMORY_SCOPE_AGENT);
      if (!b1)
        v1 = __hip_atomic_load(&src[tid + NTHR], __ATOMIC_RELAXED,
                               __HIP_MEMORY_SCOPE_AGENT);
    }
    lds_hf[lp * HDIM + tid] = __uint_as_float((unsigned)v0);
    lds_hf[lp * HDIM + tid + NTHR] = __uint_as_float((unsigned)v1);
    if (tid < EDIM) lds_xbuf[lp][tid] = xv;
    __syncthreads();

    // ---- h fragment: 8 contiguous float4s, reused across the 4 rows
    const float4* hb = lds_h4 + lp * 256;
    float4 hv0 = hb[sl], hv1 = hb[sl + 32], hv2 = hb[sl + 64],
           hv3 = hb[sl + 96], hv4 = hb[sl + 128], hv5 = hb[sl + 160],
           hv6 = hb[sl + 192], hv7 = hb[sl + 224];

#define ROWDOT(dst, srcp)                                                 \
  {                                                                       \
    float4 a = (srcp)[sl], b = (srcp)[sl + 32], c = (srcp)[sl + 64],      \
           d = (srcp)[sl + 96], e4 = (srcp)[sl + 128],                    \
           f4 = (srcp)[sl + 160], g4 = (srcp)[sl + 192],                  \
           i4 = (srcp)[sl + 224];                                         \
    dst = (a.x * hv0.x + a.y * hv0.y + a.z * hv0.z + a.w * hv0.w) +       \
          (b.x * hv1.x + b.y * hv1.y + b.z * hv1.z + b.w * hv1.w) +       \
          (c.x * hv2.x + c.y * hv2.y + c.z * hv2.z + c.w * hv2.w) +       \
          (d.x * hv3.x + d.y * hv3.y + d.z * hv3.z + d.w * hv3.w) +       \
          (e4.x * hv4.x + e4.y * hv4.y + e4.z * hv4.z + e4.w * hv4.w) +   \
          (f4.x * hv5.x + f4.y * hv5.y + f4.z * hv5.z + f4.w * hv5.w) +   \
          (g4.x * hv6.x + g4.y * hv6.y + g4.z * hv6.z + g4.w * hv6.w) +   \
          (i4.x * hv7.x + i4.y * hv7.y + i4.z * hv7.z + i4.w * hv7.w);    \
  }

    float acc0, acc1, acc2, acc3;
    if (lu < 8) {
      ROWDOT(acc0, wl0);
      ROWDOT(acc1, wl1);
      ROWDOT(acc2, wl2);
      ROWDOT(acc3, wl3);
    } else {
      ROWDOT(acc0, gg0);
      ROWDOT(acc1, gg1);
      ROWDOT(acc2, gg2);
      ROWDOT(acc3, gg3);
    }
#undef ROWDOT

    // ---- fold x-projection + biases (lane sl<4 pre-adds into acc_{sl})
    if (sl < 4) {
      int lrow = lu * 4 + sl;
      float xd = lds_bsum[lrow];
#pragma unroll
      for (int e = 0; e < EDIM; ++e) xd += lds_wih[lrow][e] * lds_xbuf[lp][e];
      if (sl == 0) acc0 += xd;
      else if (sl == 1) acc1 += xd;
      else if (sl == 2) acc2 += xd;
      else acc3 += xd;
    }

    // ---- in-half reduce (xor masks 1..16 stay within the 32-lane half)
#pragma unroll
    for (int m = 1; m < 32; m <<= 1) {
      acc0 += __shfl_xor(acc0, m);
      acc1 += __shfl_xor(acc1, m);
      acc2 += __shfl_xor(acc2, m);
      acc3 += __shfl_xor(acc3, m);
    }

    // ---- activations: lanes 0..3 of each half, one exp chain each
    float pre = (myg == 0) ? acc0 : (myg == 1) ? acc1 : (myg == 2) ? acc2
                                                                   : acc3;
    float e = __expf(-gsc * pre);
    float y = 1.f / (1.f + e);
    float act = (myg == 2) ? 2.f * y - 1.f : y;

    int base = lane & 32;
    float ai = __shfl(act, base + 0);
    float af = __shfl(act, base + 1);
    float ag = __shfl(act, base + 2);
    float ao = __shfl(act, base + 3);
    if (sl == 0) {
      cst = af * cst + ai * ag;
      float e2 = __expf(-2.f * cst);
      float hn = ao * (2.f / (1.f + e2) - 1.f);
      ull pk = ((ull)(unsigned)t << 32) | (ull)__float_as_uint(hn);
      __hip_atomic_store(&hrec[(size_t)(t & 3) * HDIM + UPW * w + lu], pk,
                         __ATOMIC_RELAXED, __HIP_MEMORY_SCOPE_AGENT);
    }
    // no end-of-step barrier: publish is self-validating; LDS h parity is
    // reused 2 steps later, ordered by the intervening step's barrier.
  }

  // ---- tail step 1: u = tanh(W1 @ h_T + b1), 8 rows per WG ---------------
  {
    const unsigned want = (unsigned)TSTEPS;  // parity (TSTEPS & 3) == 0
    ull v0 = __hip_atomic_load(&hrec[tid], __ATOMIC_RELAXED,
                               __HIP_MEMORY_SCOPE_AGENT);
    ull v1 = __hip_atomic_load(&hrec[tid + NTHR], __ATOMIC_RELAXED,
                               __HIP_MEMORY_SCOPE_AGENT);
    for (;;) {
      bool b0 = (unsigned)(v0 >> 32) == want;
      bool b1 = (unsigned)(v1 >> 32) == want;
      if (b0 && b1) break;
      if (!b0)
        v0 = __hip_atomic_load(&hrec[tid], __ATOMIC_RELAXED,
                               __HIP_MEMORY_SCOPE_AGENT);
      if (!b1)
        v1 = __hip_atomic_load(&hrec[tid + NTHR], __ATOMIC_RELAXED,
                               __HIP_MEMORY_SCOPE_AGENT);
    }
    lds_hf[tid] = __uint_as_float((unsigned)v0);
    lds_hf[tid + NTHR] = __uint_as_float((unsigned)v1);
  }
  __syncthreads();
  {
    int r1 = 8 * w + wave;  // one MLP row per wave, 512 rows over 64 WGs
    const float* w1p = W1 + (size_t)r1 * HDIM + lane * 16;
    float a0 = 0.f, a1 = 0.f;
#pragma unroll
    for (int i = 0; i < 16; i += 2) {
      a0 += w1p[i] * lds_hf[lane * 16 + i];
      a1 += w1p[i + 1] * lds_hf[lane * 16 + i + 1];
    }
    float acc1 = a0 + a1;
#pragma unroll
    for (int m = 1; m < 64; m <<= 1) acc1 += __shfl_xor(acc1, m);
    if (lane == 0) {
      float e2 = __expf(-2.f * (acc1 + b1[r1]));
      float u = 2.f / (1.f + e2) - 1.f;
      ull pk = (1ull << 32) | (ull)__float_as_uint(u);
      __hip_atomic_store(&urec[r1], pk, __ATOMIC_RELAXED,
                         __HIP_MEMORY_SCOPE_AGENT);
    }
  }

  // ---- tail step 2: out = W2 @ u + b2, WG 0 only -------------------------
  if (w == 0) {
    ull uv = __hip_atomic_load(&urec[tid], __ATOMIC_RELAXED,
                               __HIP_MEMORY_SCOPE_AGENT);
    while ((unsigned)(uv >> 32) != 1u)
      uv = __hip_atomic_load(&urec[tid], __ATOMIC_RELAXED,
                             __HIP_MEMORY_SCOPE_AGENT);
    float u = __uint_as_float((unsigned)uv);
    float p0 = W2[tid] * u;
    float p1 = W2[HLDIM + tid] * u;
#pragma unroll
    for (int m = 1; m < 64; m <<= 1) {
      p0 += __shfl_xor(p0, m);
      p1 += __shfl_xor(p1, m);
    }
    __syncthreads();
    if (lane == 0) {
      lds_r0[wave] = p0;
      lds_r1[wave] = p1;
    }
    __syncthreads();
    if (tid == 0) {
      float o0 = b2[0], o1 = b2[1];
#pragma unroll
      for (int k = 0; k < 8; ++k) {
        o0 += lds_r0[k];
        o1 += lds_r1[k];
      }
      out[0] = o0;
      out[1] = o1;
    }
  }
}

extern "C" void kernel_launch(void* const* d_in, const int* in_sizes, int n_in,
                              void* d_out, int out_size, void* d_ws,
                              size_t ws_size, hipStream_t stream) {
  const float* x = (const float*)d_in[0];
  const float* h0 = (const float*)d_in[1];
  const float* c0 = (const float*)d_in[2];
  const float* Wih = (const float*)d_in[3];
  const float* Whh = (const float*)d_in[4];
  const float* bih = (const float*)d_in[5];
  const float* bhh = (const float*)d_in[6];
  const float* W1 = (const float*)d_in[7];
  const float* b1 = (const float*)d_in[8];
  const float* W2 = (const float*)d_in[9];
  const float* b2 = (const float*)d_in[10];
  float* out = (float*)d_out;

  ull* hrec = (ull*)d_ws;                                    // 4*1024*8 = 32 KB
  ull* urec = (ull*)((char*)d_ws + 4 * HDIM * sizeof(ull));  // 4 KB

  k_init<<<1, 1024, 0, stream>>>(h0, hrec, urec);
  k_main<<<NWG, NTHR, 0, stream>>>(x, c0, Wih, Whh, bih, bhh, W1, b1, W2, b2,
                                   out, hrec, urec);
}

// Round 9
// 56879.822 us; speedup vs baseline: 1.5325x; 1.0470x over previous
//
#include <hip/hip_runtime.h>
#include <cstdint>
#include <cstddef>

#define NWG 64
#define NTHR 512
#define UPW 16  // hidden units per WG
#define TSTEPS 16384
#define HDIM 1024
#define EDIM 13
#define HLDIM 512

typedef unsigned long long ull;

// ---------------------------------------------------------------------------
// Init kernel: re-arm the tagged h-record ring and u-record every call (d_ws
// is poisoned once with 0xAA and never re-poisoned between graph replays; a
// finished replay also leaves end-state tags behind, so every tag word must
// be rewritten each launch).
// hrec[parity][i] = { low32: f32 h value, high32: u32 step tag }, 4 parities.
// ---------------------------------------------------------------------------
__global__ void k_init(const float* __restrict__ h0, ull* __restrict__ hrec,
                       ull* __restrict__ urec) {
  int i = threadIdx.x;  // 1024 threads
  hrec[i] = (ull)__float_as_uint(h0[i]);  // {h0, tag=0}
  hrec[HDIM + i] = 0ull;
  hrec[2 * HDIM + i] = 0ull;
  hrec[3 * HDIM + i] = 0ull;
  if (i < HLDIM) urec[i] = 0ull;
}

// ---------------------------------------------------------------------------
// Persistent LSTM kernel. R8 body + ONE change: single-wave polling.
// R8 post-mortem: per-step wall ~3us, of which only ~0.2us is VALU work; the
// rest is waiting. Suspected MALL contention: 512 threads/WG x 64 WGs all
// issuing coherent 8B probe loads every RTT, every wave draining vmcnt on
// its own probes before the barrier. Fix: wave 0 polls ALL 1024 records
// (16/lane, distinct addresses -> one pipelined RTT per probe round), fills
// LDS, barrier releases waves 1-7 which never touch the coherent path.
// (Also learned: LDS bank conflicts were a mis-scaling - 32cyc/step/CU,
// irrelevant; W-path streaming is not the wall either - R4 streamed more
// from scratch and was faster.)
// W residency: units 0..7 in 128 KB LDS, units 8..15 streamed from L2
// (1 MB/XCD working set). Cross-WG sync: self-validating {value, tag}
// records, 4-deep parity ring, relaxed agent-scope atomics (single-copy,
// serviced at the device coherent point -> immune to non-coherent per-XCD
// L2s). One poll + one barrier per step.
// ---------------------------------------------------------------------------
__global__ __launch_bounds__(NTHR) void k_main(
    const float* __restrict__ x, const float* __restrict__ c0,
    const float* __restrict__ Wih, const float* __restrict__ Whh,
    const float* __restrict__ bih, const float* __restrict__ bhh,
    const float* __restrict__ W1, const float* __restrict__ b1,
    const float* __restrict__ W2, const float* __restrict__ b2,
    float* __restrict__ out, ull* hrec, ull* urec) {
  const int w = blockIdx.x;
  const int tid = threadIdx.x;
  const int wave = tid >> 6;     // 0..7
  const int lane = tid & 63;
  const int hi = lane >> 5;      // 0/1: which unit of the wave
  const int sl = lane & 31;      // sub-lane within the half
  const int lu = 2 * wave + hi;  // local unit 0..15

  __shared__ float4 lds_w4[32 * 256];  // units 0..7: row r=4*lu+g, 128 KB
  __shared__ float4 lds_h4[2 * 256];   // [parity][col4]
  __shared__ float lds_wih[64][17];    // row = 4*lu+g, stride 17
  __shared__ float lds_bsum[64];
  __shared__ float lds_r0[8], lds_r1[8];
  __shared__ float lds_xbuf[2][16];
  float* lds_hf = (float*)lds_h4;  // [2][1024] flat

  // ---- stage W for units 0..7 into LDS (one-time, coalesced) -------------
#pragma unroll
  for (int it = 0; it < 16; ++it) {
    int idx = it * NTHR + tid;  // 0..8191 float4s
    int r = idx >> 8;           // LDS row 0..31 (r = 4*lu + g)
    int c4 = idx & 255;
    int lu_ = r >> 2, g_ = r & 3;
    int grow = g_ * HDIM + UPW * w + lu_;
    lds_w4[r * 256 + c4] = ((const float4*)(Whh + (size_t)grow * HDIM))[c4];
  }
  if (tid < 64) {
    int lu_ = tid >> 2, g_ = tid & 3;
    int grow = g_ * HDIM + UPW * w + lu_;
#pragma unroll
    for (int e = 0; e < EDIM; ++e) lds_wih[tid][e] = Wih[grow * EDIM + e];
    lds_bsum[tid] = bih[grow] + bhh[grow];
  }
  // cell state: lane sl==0 of each half owns unit 16w+lu
  float cst = c0[UPW * w + lu];
  __syncthreads();

  const int myg = sl & 3;                    // gate computed by lanes 0..3
  const float gsc = (myg == 2) ? 2.f : 1.f;  // tanh via 2*sigmoid(2x)-1
  // W sources: LDS rows for lu<8, global rows (L2-resident) for lu>=8
  const float4* wl0 = lds_w4 + (size_t)(4 * lu + 0) * 256;  // lu<8 only
  const float4* wl1 = lds_w4 + (size_t)(4 * lu + 1) * 256;
  const float4* wl2 = lds_w4 + (size_t)(4 * lu + 2) * 256;
  const float4* wl3 = lds_w4 + (size_t)(4 * lu + 3) * 256;
  const float4* gg0 =
      (const float4*)(Whh + (size_t)(0 * HDIM + UPW * w + lu) * HDIM);
  const float4* gg1 =
      (const float4*)(Whh + (size_t)(1 * HDIM + UPW * w + lu) * HDIM);
  const float4* gg2 =
      (const float4*)(Whh + (size_t)(2 * HDIM + UPW * w + lu) * HDIM);
  const float4* gg3 =
      (const float4*)(Whh + (size_t)(3 * HDIM + UPW * w + lu) * HDIM);

  for (int t = 1; t <= TSTEPS; ++t) {
    const int lp = (t - 1) & 1;

    // ---- single-wave poll: wave 0 fetches all 1024 {h, tag} records ------
    if (wave == 0) {
      // x_t prefetch on lanes 0..12, issued before the poll loop
      float xv = 0.f;
      if (lane < EDIM) xv = x[(size_t)(t - 1) * EDIM + lane];

      const ull* src = hrec + (size_t)((t - 1) & 3) * HDIM;
      const unsigned want = (unsigned)(t - 1);
      ull v0, v1, v2, v3, v4, v5, v6, v7, v8, v9, va, vb, vc, vd, ve, vf;
      for (;;) {
        // 16 distinct-address coherent loads, issued back-to-back: one
        // pipelined RTT per probe round, always the freshest values.
        v0 = __hip_atomic_load(&src[lane], __ATOMIC_RELAXED,
                               __HIP_MEMORY_SCOPE_AGENT);
        v1 = __hip_atomic_load(&src[lane + 64], __ATOMIC_RELAXED,
                               __HIP_MEMORY_SCOPE_AGENT);
        v2 = __hip_atomic_load(&src[lane + 128], __ATOMIC_RELAXED,
                               __HIP_MEMORY_SCOPE_AGENT);
        v3 = __hip_atomic_load(&src[lane + 192], __ATOMIC_RELAXED,
                               __HIP_MEMORY_SCOPE_AGENT);
        v4 = __hip_atomic_load(&src[lane + 256], __ATOMIC_RELAXED,
                               __HIP_MEMORY_SCOPE_AGENT);
        v5 = __hip_atomic_load(&src[lane + 320], __ATOMIC_RELAXED,
                               __HIP_MEMORY_SCOPE_AGENT);
        v6 = __hip_atomic_load(&src[lane + 384], __ATOMIC_RELAXED,
                               __HIP_MEMORY_SCOPE_AGENT);
        v7 = __hip_atomic_load(&src[lane + 448], __ATOMIC_RELAXED,
                               __HIP_MEMORY_SCOPE_AGENT);
        v8 = __hip_atomic_load(&src[lane + 512], __ATOMIC_RELAXED,
                               __HIP_MEMORY_SCOPE_AGENT);
        v9 = __hip_atomic_load(&src[lane + 576], __ATOMIC_RELAXED,
                               __HIP_MEMORY_SCOPE_AGENT);
        va = __hip_atomic_load(&src[lane + 640], __ATOMIC_RELAXED,
                               __HIP_MEMORY_SCOPE_AGENT);
        vb = __hip_atomic_load(&src[lane + 704], __ATOMIC_RELAXED,
                               __HIP_MEMORY_SCOPE_AGENT);
        vc = __hip_atomic_load(&src[lane + 768], __ATOMIC_RELAXED,
                               __HIP_MEMORY_SCOPE_AGENT);
        vd = __hip_atomic_load(&src[lane + 832], __ATOMIC_RELAXED,
                               __HIP_MEMORY_SCOPE_AGENT);
        ve = __hip_atomic_load(&src[lane + 896], __ATOMIC_RELAXED,
                               __HIP_MEMORY_SCOPE_AGENT);
        vf = __hip_atomic_load(&src[lane + 960], __ATOMIC_RELAXED,
                               __HIP_MEMORY_SCOPE_AGENT);
        unsigned ok = ((unsigned)(v0 >> 32) == want) &
                      ((unsigned)(v1 >> 32) == want) &
                      ((unsigned)(v2 >> 32) == want) &
                      ((unsigned)(v3 >> 32) == want) &
                      ((unsigned)(v4 >> 32) == want) &
                      ((unsigned)(v5 >> 32) == want) &
                      ((unsigned)(v6 >> 32) == want) &
                      ((unsigned)(v7 >> 32) == want) &
                      ((unsigned)(v8 >> 32) == want) &
                      ((unsigned)(v9 >> 32) == want) &
                      ((unsigned)(va >> 32) == want) &
                      ((unsigned)(vb >> 32) == want) &
                      ((unsigned)(vc >> 32) == want) &
                      ((unsigned)(vd >> 32) == want) &
                      ((unsigned)(ve >> 32) == want) &
                      ((unsigned)(vf >> 32) == want);
        if (ok) break;
      }
      float* dst = lds_hf + lp * HDIM + lane;
      dst[0] = __uint_as_float((unsigned)v0);
      dst[64] = __uint_as_float((unsigned)v1);
      dst[128] = __uint_as_float((unsigned)v2);
      dst[192] = __uint_as_float((unsigned)v3);
      dst[256] = __uint_as_float((unsigned)v4);
      dst[320] = __uint_as_float((unsigned)v5);
      dst[384] = __uint_as_float((unsigned)v6);
      dst[448] = __uint_as_float((unsigned)v7);
      dst[512] = __uint_as_float((unsigned)v8);
      dst[576] = __uint_as_float((unsigned)v9);
      dst[640] = __uint_as_float((unsigned)va);
      dst[704] = __uint_as_float((unsigned)vb);
      dst[768] = __uint_as_float((unsigned)vc);
      dst[832] = __uint_as_float((unsigned)vd);
      dst[896] = __uint_as_float((unsigned)ve);
      dst[960] = __uint_as_float((unsigned)vf);
      if (lane < EDIM) lds_xbuf[lp][lane] = xv;
    }
    __syncthreads();

    // ---- h fragment: 8 contiguous float4s, reused across the 4 rows
    const float4* hb = lds_h4 + lp * 256;
    float4 hv0 = hb[sl], hv1 = hb[sl + 32], hv2 = hb[sl + 64],
           hv3 = hb[sl + 96], hv4 = hb[sl + 128], hv5 = hb[sl + 160],
           hv6 = hb[sl + 192], hv7 = hb[sl + 224];

#define ROWDOT(dst, srcp)                                               \
  {                                                                     \
    float4 a = (srcp)[sl], b = (srcp)[sl + 32], c = (srcp)[sl + 64],    \
           d = (srcp)[sl + 96], e4 = (srcp)[sl + 128],                  \
           f4 = (srcp)[sl + 160], g4 = (srcp)[sl + 192],                \
           i4 = (srcp)[sl + 224];                                       \
    dst = (a.x * hv0.x + a.y * hv0.y + a.z * hv0.z + a.w * hv0.w) +     \
          (b.x * hv1.x + b.y * hv1.y + b.z * hv1.z + b.w * hv1.w) +     \
          (c.x * hv2.x + c.y * hv2.y + c.z * hv2.z + c.w * hv2.w) +     \
          (d.x * hv3.x + d.y * hv3.y + d.z * hv3.z + d.w * hv3.w) +     \
          (e4.x * hv4.x + e4.y * hv4.y + e4.z * hv4.z + e4.w * hv4.w) + \
          (f4.x * hv5.x + f4.y * hv5.y + f4.z * hv5.z + f4.w * hv5.w) + \
          (g4.x * hv6.x + g4.y * hv6.y + g4.z * hv6.z + g4.w * hv6.w) + \
          (i4.x * hv7.x + i4.y * hv7.y + i4.z * hv7.z + i4.w * hv7.w);  \
  }

    float acc0, acc1, acc2, acc3;
    if (lu < 8) {
      ROWDOT(acc0, wl0);
      ROWDOT(acc1, wl1);
      ROWDOT(acc2, wl2);
      ROWDOT(acc3, wl3);
    } else {
      ROWDOT(acc0, gg0);
      ROWDOT(acc1, gg1);
      ROWDOT(acc2, gg2);
      ROWDOT(acc3, gg3);
    }
#undef ROWDOT

    // ---- fold x-projection + biases (lane sl<4 pre-adds into acc_{sl})
    if (sl < 4) {
      int lrow = lu * 4 + sl;
      float xd = lds_bsum[lrow];
#pragma unroll
      for (int e = 0; e < EDIM; ++e) xd += lds_wih[lrow][e] * lds_xbuf[lp][e];
      if (sl == 0) acc0 += xd;
      else if (sl == 1) acc1 += xd;
      else if (sl == 2) acc2 += xd;
      else acc3 += xd;
    }

    // ---- in-half reduce (xor masks 1..16 stay within the 32-lane half)
#pragma unroll
    for (int m = 1; m < 32; m <<= 1) {
      acc0 += __shfl_xor(acc0, m);
      acc1 += __shfl_xor(acc1, m);
      acc2 += __shfl_xor(acc2, m);
      acc3 += __shfl_xor(acc3, m);
    }

    // ---- activations: lanes 0..3 of each half, one exp chain each
    float pre = (myg == 0) ? acc0 : (myg == 1) ? acc1 : (myg == 2) ? acc2
                                                                   : acc3;
    float e = __expf(-gsc * pre);
    float y = 1.f / (1.f + e);
    float act = (myg == 2) ? 2.f * y - 1.f : y;

    int base = lane & 32;
    float ai = __shfl(act, base + 0);
    float af = __shfl(act, base + 1);
    float ag = __shfl(act, base + 2);
    float ao = __shfl(act, base + 3);
    if (sl == 0) {
      cst = af * cst + ai * ag;
      float e2 = __expf(-2.f * cst);
      float hn = ao * (2.f / (1.f + e2) - 1.f);
      ull pk = ((ull)(unsigned)t << 32) | (ull)__float_as_uint(hn);
      __hip_atomic_store(&hrec[(size_t)(t & 3) * HDIM + UPW * w + lu], pk,
                         __ATOMIC_RELAXED, __HIP_MEMORY_SCOPE_AGENT);
    }
    // no end-of-step barrier: publish is self-validating; LDS h parity is
    // reused 2 steps later, ordered by the intervening step's barrier.
  }

  // ---- tail step 1: u = tanh(W1 @ h_T + b1), 8 rows per WG ---------------
  {
    const unsigned want = (unsigned)TSTEPS;  // parity (TSTEPS & 3) == 0
    ull v0 = __hip_atomic_load(&hrec[tid], __ATOMIC_RELAXED,
                               __HIP_MEMORY_SCOPE_AGENT);
    ull v1 = __hip_atomic_load(&hrec[tid + NTHR], __ATOMIC_RELAXED,
                               __HIP_MEMORY_SCOPE_AGENT);
    for (;;) {
      bool b0 = (unsigned)(v0 >> 32) == want;
      bool b1 = (unsigned)(v1 >> 32) == want;
      if (b0 && b1) break;
      if (!b0)
        v0 = __hip_atomic_load(&hrec[tid], __ATOMIC_RELAXED,
                               __HIP_MEMORY_SCOPE_AGENT);
      if (!b1)
        v1 = __hip_atomic_load(&hrec[tid + NTHR], __ATOMIC_RELAXED,
                               __HIP_MEMORY_SCOPE_AGENT);
    }
    lds_hf[tid] = __uint_as_float((unsigned)v0);
    lds_hf[tid + NTHR] = __uint_as_float((unsigned)v1);
  }
  __syncthreads();
  {
    int r1 = 8 * w + wave;  // one MLP row per wave, 512 rows over 64 WGs
    const float* w1p = W1 + (size_t)r1 * HDIM + lane * 16;
    float a0 = 0.f, a1 = 0.f;
#pragma unroll
    for (int i = 0; i < 16; i += 2) {
      a0 += w1p[i] * lds_hf[lane * 16 + i];
      a1 += w1p[i + 1] * lds_hf[lane * 16 + i + 1];
    }
    float acc1 = a0 + a1;
#pragma unroll
    for (int m = 1; m < 64; m <<= 1) acc1 += __shfl_xor(acc1, m);
    if (lane == 0) {
      float e2 = __expf(-2.f * (acc1 + b1[r1]));
      float u = 2.f / (1.f + e2) - 1.f;
      ull pk = (1ull << 32) | (ull)__float_as_uint(u);
      __hip_atomic_store(&urec[r1], pk, __ATOMIC_RELAXED,
                         __HIP_MEMORY_SCOPE_AGENT);
    }
  }

  // ---- tail step 2: out = W2 @ u + b2, WG 0 only -------------------------
  if (w == 0) {
    ull uv = __hip_atomic_load(&urec[tid], __ATOMIC_RELAXED,
                               __HIP_MEMORY_SCOPE_AGENT);
    while ((unsigned)(uv >> 32) != 1u)
      uv = __hip_atomic_load(&urec[tid], __ATOMIC_RELAXED,
                             __HIP_MEMORY_SCOPE_AGENT);
    float u = __uint_as_float((unsigned)uv);
    float p0 = W2[tid] * u;
    float p1 = W2[HLDIM + tid] * u;
#pragma unroll
    for (int m = 1; m < 64; m <<= 1) {
      p0 += __shfl_xor(p0, m);
      p1 += __shfl_xor(p1, m);
    }
    if (lane == 0) {
      lds_r0[wave] = p0;
      lds_r1[wave] = p1;
    }
    __syncthreads();
    if (tid == 0) {
      float o0 = b2[0], o1 = b2[1];
#pragma unroll
      for (int k = 0; k < 8; ++k) {
        o0 += lds_r0[k];
        o1 += lds_r1[k];
      }
      out[0] = o0;
      out[1] = o1;
    }
  }
}

extern "C" void kernel_launch(void* const* d_in, const int* in_sizes, int n_in,
                              void* d_out, int out_size, void* d_ws,
                              size_t ws_size, hipStream_t stream) {
  const float* x = (const float*)d_in[0];
  const float* h0 = (const float*)d_in[1];
  const float* c0 = (const float*)d_in[2];
  const float* Wih = (const float*)d_in[3];
  const float* Whh = (const float*)d_in[4];
  const float* bih = (const float*)d_in[5];
  const float* bhh = (const float*)d_in[6];
  const float* W1 = (const float*)d_in[7];
  const float* b1 = (const float*)d_in[8];
  const float* W2 = (const float*)d_in[9];
  const float* b2 = (const float*)d_in[10];
  float* out = (float*)d_out;

  ull* hrec = (ull*)d_ws;                                    // 4*1024*8 = 32 KB
  ull* urec = (ull*)((char*)d_ws + 4 * HDIM * sizeof(ull));  // 4 KB

  k_init<<<1, 1024, 0, stream>>>(h0, hrec, urec);
  k_main<<<NWG, NTHR, 0, stream>>>(x, c0, Wih, Whh, bih, bhh, W1, b1, W2, b2,
                                   out, hrec, urec);
}